// Round 1
// baseline (823.054 us; speedup 1.0000x reference)
//
#include <hip/hip_runtime.h>
#include <hip/hip_bf16.h>
#include <math.h>

#define N_ENVS   4096
#define N_AGENTS 64
#define OBS_DIM  256
#define HIDDEN   512
#define HEADK    32
#define BE       64   // envs per block

typedef __attribute__((ext_vector_type(8))) short bf16x8;
typedef __attribute__((ext_vector_type(8))) unsigned short u16x8;
typedef __attribute__((ext_vector_type(4))) float f32x4;

static __device__ __forceinline__ unsigned short f2bf(float x) {
    union { float f; unsigned int u; } v; v.f = x;
    unsigned int r = (v.u + 0x7FFFu + ((v.u >> 16) & 1u)) >> 16;
    return (unsigned short)r;
}

// Convert + transpose weights to bf16, N-major (so B-fragments are 16B contiguous).
__global__ void prep_weights_kernel(const float* __restrict__ W1,
                                    const float* __restrict__ W2,
                                    const float* __restrict__ HW1,
                                    unsigned short* __restrict__ W1T,
                                    unsigned short* __restrict__ W2T,
                                    unsigned short* __restrict__ HW1T) {
    int id = blockIdx.x * 256 + threadIdx.x;
    if (id < 131072) {                      // W1 [256][512] -> W1T [512][256]
        int k = id >> 9, n = id & 511;
        W1T[n * 256 + k] = f2bf(W1[id]);
    } else if (id < 131072 + 262144) {      // W2 [512][512] -> W2T [512][512]
        int t = id - 131072;
        int k = t >> 9, n = t & 511;
        W2T[n * 512 + k] = f2bf(W2[t]);
    } else if (id < 131072 + 262144 + 1048576) {  // HW1 [64][512][32] -> HW1T [64][32][512]
        int t = id - (131072 + 262144);
        int ag = t >> 14;
        int rem = t & 16383;
        int hh = rem >> 5, c = rem & 31;
        HW1T[((ag << 5) + c) * 512 + hh] = f2bf(HW1[t]);
    }
}

// Fused: obs -> (GEMM1 relu) -> (GEMM2 relu) -> per-agent head1 relu -> head2 sigmoid.
// Block = 64 envs x 1 agent. 512 threads = 8 waves (2 row x 4 col).
__launch_bounds__(512, 1)
__global__ void fused_mlp_kernel(const float* __restrict__ obs,
                                 const float* __restrict__ b1,
                                 const float* __restrict__ b2,
                                 const float* __restrict__ Hb1,
                                 const float* __restrict__ HW2,
                                 const float* __restrict__ Hb2,
                                 const unsigned short* __restrict__ W1T,
                                 const unsigned short* __restrict__ W2T,
                                 const unsigned short* __restrict__ HW1T,
                                 float* __restrict__ out) {
    // lds0: first 32KB = obs tile [64][256] bf16; later reused as feat [64][512] bf16
    __shared__ unsigned short lds0[BE * 512];   // 64 KB
    __shared__ unsigned short ldsh[BE * 512];   // 64 KB  h [64][512] bf16
    __shared__ float ldsg[BE * 36];             // 9 KB   g [64][32] f32 (pad 36)

    const int tid  = threadIdx.x;
    const int lane = tid & 63;
    const int wid  = tid >> 6;
    const int wr   = wid >> 2;   // 0..1  (row half)
    const int wc   = wid & 3;    // 0..3  (col quarter)
    const int l15  = lane & 15;
    const int lk   = lane >> 4;  // 0..3
    const int e0   = blockIdx.x * BE;
    const int ag   = blockIdx.y;

    // ---------------- stage obs tile (fp32 -> bf16, swizzled) ----------------
    {
        const float* src = obs + (size_t)e0 * (N_AGENTS * OBS_DIM) + (size_t)ag * OBS_DIM;
        #pragma unroll
        for (int g = 0; g < 4; ++g) {
            int gi  = tid + 512 * g;            // 2048 groups of 8 elems
            int row = gi >> 5;                  // 32 groups per row
            int kg  = (gi & 31) << 3;
            const float4* p = reinterpret_cast<const float4*>(src + (size_t)row * (N_AGENTS * OBS_DIM) + kg);
            float4 v0 = p[0], v1 = p[1];
            u16x8 w;
            w[0] = f2bf(v0.x); w[1] = f2bf(v0.y); w[2] = f2bf(v0.z); w[3] = f2bf(v0.w);
            w[4] = f2bf(v1.x); w[5] = f2bf(v1.y); w[6] = f2bf(v1.z); w[7] = f2bf(v1.w);
            int byt = (row * 512 + kg * 2) ^ ((row & 7) << 4);
            *reinterpret_cast<u16x8*>(&lds0[byt >> 1]) = w;
        }
    }
    __syncthreads();

    const f32x4 fzero = {0.f, 0.f, 0.f, 0.f};

    // ---------------- GEMM1: h = relu(obs @ W1 + b1), K=256 ----------------
    f32x4 acc[2][8];
    #pragma unroll
    for (int i = 0; i < 2; ++i)
        #pragma unroll
        for (int j = 0; j < 8; ++j) acc[i][j] = fzero;

    #pragma unroll 2
    for (int ks = 0; ks < 8; ++ks) {
        const int kk = ks * 32 + lk * 8;
        bf16x8 af[2];
        #pragma unroll
        for (int mi = 0; mi < 2; ++mi) {
            int row = wr * 32 + mi * 16 + l15;
            int byt = (row * 512 + kk * 2) ^ ((row & 7) << 4);
            af[mi] = *reinterpret_cast<const bf16x8*>(&lds0[byt >> 1]);
        }
        #pragma unroll
        for (int ni = 0; ni < 8; ++ni) {
            int col = wc * 128 + ni * 16 + l15;
            bf16x8 bf = *reinterpret_cast<const bf16x8*>(&W1T[col * 256 + kk]);
            acc[0][ni] = __builtin_amdgcn_mfma_f32_16x16x32_bf16(af[0], bf, acc[0][ni], 0, 0, 0);
            acc[1][ni] = __builtin_amdgcn_mfma_f32_16x16x32_bf16(af[1], bf, acc[1][ni], 0, 0, 0);
        }
    }
    // epilogue: +b1, relu, write h (bf16, swizzled)
    #pragma unroll
    for (int mi = 0; mi < 2; ++mi)
        #pragma unroll
        for (int ni = 0; ni < 8; ++ni) {
            int col = wc * 128 + ni * 16 + l15;
            float bias = b1[col];
            #pragma unroll
            for (int r = 0; r < 4; ++r) {
                int row = wr * 32 + mi * 16 + lk * 4 + r;
                float v = acc[mi][ni][r] + bias;
                v = v > 0.f ? v : 0.f;
                int byt = (row * 1024 + col * 2) ^ ((row & 7) << 4);
                ldsh[byt >> 1] = f2bf(v);
            }
        }
    __syncthreads();

    // ---------------- GEMM2: feat = relu(h @ W2 + b2), K=512 ----------------
    #pragma unroll
    for (int i = 0; i < 2; ++i)
        #pragma unroll
        for (int j = 0; j < 8; ++j) acc[i][j] = fzero;

    #pragma unroll 2
    for (int ks = 0; ks < 16; ++ks) {
        const int kk = ks * 32 + lk * 8;
        bf16x8 af[2];
        #pragma unroll
        for (int mi = 0; mi < 2; ++mi) {
            int row = wr * 32 + mi * 16 + l15;
            int byt = (row * 1024 + kk * 2) ^ ((row & 7) << 4);
            af[mi] = *reinterpret_cast<const bf16x8*>(&ldsh[byt >> 1]);
        }
        #pragma unroll
        for (int ni = 0; ni < 8; ++ni) {
            int col = wc * 128 + ni * 16 + l15;
            bf16x8 bf = *reinterpret_cast<const bf16x8*>(&W2T[col * 512 + kk]);
            acc[0][ni] = __builtin_amdgcn_mfma_f32_16x16x32_bf16(af[0], bf, acc[0][ni], 0, 0, 0);
            acc[1][ni] = __builtin_amdgcn_mfma_f32_16x16x32_bf16(af[1], bf, acc[1][ni], 0, 0, 0);
        }
    }
    // epilogue: +b2, relu, write feat into lds0 (obs dead after barrier 2)
    #pragma unroll
    for (int mi = 0; mi < 2; ++mi)
        #pragma unroll
        for (int ni = 0; ni < 8; ++ni) {
            int col = wc * 128 + ni * 16 + l15;
            float bias = b2[col];
            #pragma unroll
            for (int r = 0; r < 4; ++r) {
                int row = wr * 32 + mi * 16 + lk * 4 + r;
                float v = acc[mi][ni][r] + bias;
                v = v > 0.f ? v : 0.f;
                int byt = (row * 1024 + col * 2) ^ ((row & 7) << 4);
                lds0[byt >> 1] = f2bf(v);
            }
        }
    __syncthreads();

    // ---------------- head1: g = relu(feat @ HW1[ag] + Hb1[ag]), N=32 ----------------
    if (wc < 2) {
        f32x4 hacc[2] = {fzero, fzero};
        const int col = wc * 16 + l15;
        #pragma unroll 2
        for (int ks = 0; ks < 16; ++ks) {
            const int kk = ks * 32 + lk * 8;
            bf16x8 bfh = *reinterpret_cast<const bf16x8*>(&HW1T[((ag << 5) + col) * 512 + kk]);
            #pragma unroll
            for (int mi = 0; mi < 2; ++mi) {
                int row = wr * 32 + mi * 16 + l15;
                int byt = (row * 1024 + kk * 2) ^ ((row & 7) << 4);
                bf16x8 afh = *reinterpret_cast<const bf16x8*>(&lds0[byt >> 1]);
                hacc[mi] = __builtin_amdgcn_mfma_f32_16x16x32_bf16(afh, bfh, hacc[mi], 0, 0, 0);
            }
        }
        float hb = Hb1[(ag << 5) + col];
        #pragma unroll
        for (int mi = 0; mi < 2; ++mi)
            #pragma unroll
            for (int r = 0; r < 4; ++r) {
                int row = wr * 32 + mi * 16 + lk * 4 + r;
                float v = hacc[mi][r] + hb;
                ldsg[row * 36 + col] = v > 0.f ? v : 0.f;
            }
    }
    __syncthreads();

    // ---------------- head2: out = sigmoid(g . HW2[ag] + Hb2[ag]) ----------------
    if (tid < BE) {
        float x = Hb2[ag];
        #pragma unroll
        for (int j = 0; j < 32; ++j)
            x += ldsg[tid * 36 + j] * HW2[(ag << 5) + j];
        out[(size_t)(e0 + tid) * N_AGENTS + ag] = 1.f / (1.f + expf(-x));
    }
}

extern "C" void kernel_launch(void* const* d_in, const int* in_sizes, int n_in,
                              void* d_out, int out_size, void* d_ws, size_t ws_size,
                              hipStream_t stream) {
    const float* obs = (const float*)d_in[0];
    const float* W1  = (const float*)d_in[1];
    const float* b1  = (const float*)d_in[2];
    const float* W2  = (const float*)d_in[3];
    const float* b2  = (const float*)d_in[4];
    const float* HW1 = (const float*)d_in[5];
    const float* Hb1 = (const float*)d_in[6];
    const float* HW2 = (const float*)d_in[7];
    const float* Hb2 = (const float*)d_in[8];
    float* out = (float*)d_out;

    unsigned short* W1T  = (unsigned short*)d_ws;     // 131072 elems
    unsigned short* W2T  = W1T + 131072;              // 262144 elems
    unsigned short* HW1T = W2T + 262144;              // 1048576 elems

    prep_weights_kernel<<<5632, 256, 0, stream>>>(W1, W2, HW1, W1T, W2T, HW1T);

    dim3 grid(N_ENVS / BE, N_AGENTS);
    fused_mlp_kernel<<<grid, 512, 0, stream>>>(obs, b1, b2, Hb1, HW2, Hb2,
                                               W1T, W2T, HW1T, out);
}